// Round 14
// baseline (396.647 us; speedup 1.0000x reference)
//
#include <hip/hip_runtime.h>
#include <hip/hip_bf16.h>
#include <math.h>

#define N_V 100000
#define N_E 600000
#define N_F 200000
// CIN = COUT = 128, H = 32

typedef __attribute__((ext_vector_type(8))) short bf16x8;
typedef __attribute__((ext_vector_type(4))) float f32x4;

#define FUSED_BLOCKS 782                    // ceil(100000/128); 128 rows per block
#define FACE_BLOCKS 782                     // ceil(200000/256)
#define EDGE_BLOCKS 2344                    // ceil(600000/256)
#define PACK_BLOCKS 64
#define CONV_BLOCKS 6250                    // 100000*128 bf16 conversions / (256*8)

__device__ __forceinline__ unsigned short f2bf(float f) {
    unsigned int u = __builtin_bit_cast(unsigned int, f);
    u += 0x7fffu + ((u >> 16) & 1u);   // round-to-nearest-even
    return (unsigned short)(u >> 16);
}
__device__ __forceinline__ float bf2f(short s) {
    return __builtin_bit_cast(float, ((unsigned int)(unsigned short)s) << 16);
}

// --- K1: faces (normals + corner list push) + Wlin pack (+ feat->bf16 conv).
// Pinned lessons: edge atomics live in k_edge (r10); inline normal walk 6x traffic
// (r12); k_back 512x-redundant stats reduce +10us (r13).
__global__ void k_fn(const float* __restrict__ vtx, const int* __restrict__ faces,
                     const float* __restrict__ Wlin, const float* __restrict__ feat,
                     float4* __restrict__ fnbuf4,
                     int* __restrict__ head_f, int* __restrict__ next_f,
                     unsigned short* __restrict__ Wb,
                     unsigned short* __restrict__ featb) {
    int b = blockIdx.x;
    int t = threadIdx.x;
    if (b < FACE_BLOCKS) {
        int f = b * 256 + t;
        if (f >= N_F) return;
        int i0 = faces[f], i1 = faces[N_F + f], i2 = faces[2 * N_F + f];
        #pragma unroll
        for (int j = 0; j < 3; j++) {
            int v = (j == 0) ? i0 : (j == 1 ? i1 : i2);
            int c = 3 * f + j;
            int old = atomicExch(&head_f[v], c);
            next_f[c] = old;
        }
        float ax = vtx[3 * i0], ay = vtx[3 * i0 + 1], az = vtx[3 * i0 + 2];
        float bx = vtx[3 * i1] - ax, by = vtx[3 * i1 + 1] - ay, bz = vtx[3 * i1 + 2] - az;
        float cx = vtx[3 * i2] - ax, cy = vtx[3 * i2 + 1] - ay, cz = vtx[3 * i2 + 2] - az;
        float4 fn;
        fn.x = by * cz - bz * cy;
        fn.y = bz * cx - bx * cz;
        fn.z = bx * cy - by * cx;
        fn.w = 0.f;
        fnbuf4[f] = fn;
    } else if (b < FACE_BLOCKS + PACK_BLOCKS) {
        // pack Wlin (fp32 [128,128]) into bf16 MFMA B-fragment order
        int i = (b - FACE_BLOCKS) * 256 + t;   // 0..16383
        int j = i & 7;
        int lane = (i >> 3) & 63;
        int ct = (i >> 9) & 7;
        int kk = i >> 12;
        int k = kk * 32 + (lane >> 4) * 8 + j;
        int n = ct * 16 + (lane & 15);
        Wb[i] = f2bf(Wlin[k * 128 + n]);
    } else {
        // feat fp32 -> bf16 row-major copy (streamed, 8 elems/thread)
        int i = (b - FACE_BLOCKS - PACK_BLOCKS) * 256 + t;
        const float4* fp = (const float4*)(feat + (size_t)i * 8);
        float4 f0 = fp[0], f1 = fp[1];
        bf16x8 p;
        p[0] = (short)f2bf(f0.x); p[1] = (short)f2bf(f0.y);
        p[2] = (short)f2bf(f0.z); p[3] = (short)f2bf(f0.w);
        p[4] = (short)f2bf(f1.x); p[5] = (short)f2bf(f1.y);
        p[6] = (short)f2bf(f1.z); p[7] = (short)f2bf(f1.w);
        *(bf16x8*)(featb + (size_t)i * 8) = p;
    }
}

// --- K2: vertex normals via corner-list walk; float4 out (one walk per vertex) ---
__global__ void k_vnorm(const float4* __restrict__ fnbuf4,
                        const int* __restrict__ head_f, const int* __restrict__ next_f,
                        float4* __restrict__ nrm4) {
    int v = blockIdx.x * 256 + threadIdx.x;
    if (v >= N_V) return;
    float nx = 0.f, ny = 0.f, nz = 0.f;
    int c = head_f[v];
    while (c >= 0) {
        float4 fn = fnbuf4[(unsigned)c / 3u];
        nx += fn.x; ny += fn.y; nz += fn.z;
        c = next_f[c];
    }
    float inv = 1.f / (sqrtf(nx * nx + ny * ny + nz * nz) + 1e-8f);
    float4 o;
    o.x = nx * inv; o.y = ny * inv; o.z = nz * inv; o.w = 0.f;
    nrm4[v] = o;
}

// --- K3: per-edge MLP + atomicExch push (issued early; hides under MLP).
//     MODE 0: split-w pack (fallback). MODE 1: w15 pack (main) + zeroes done-counter.
template<int MODE>
__global__ void k_edge_t(const float* __restrict__ vtx, const int* __restrict__ edges,
                         const float4* __restrict__ nrm4,
                         const float* __restrict__ W1, const float* __restrict__ b1,
                         const float* __restrict__ W2, const float* __restrict__ b2,
                         int* __restrict__ head_e, uint2* __restrict__ enode,
                         unsigned int* cnt) {
    __shared__ float sW1[96], sb1[32], sW2[192], sb2[6];
    int t = threadIdx.x;
    if (t < 96)  sW1[t] = W1[t];
    if (t < 32)  sb1[t] = b1[t];
    if (t < 192) sW2[t] = W2[t];
    if (t < 6)   sb2[t] = b2[t];
    __syncthreads();
    int e = blockIdx.x * blockDim.x + t;
    if (e >= N_E) return;
    if (MODE == 1 && e == 0) *cnt = 0;        // init done-counter for k_fused last-block
    int s = edges[e], d = edges[N_E + e];
    int old = atomicExch(&head_e[d], e);      // issue early; hides under MLP
    float4 nv = nrm4[s];
    float dx = vtx[3 * d] - vtx[3 * s];
    float dy = vtx[3 * d + 1] - vtx[3 * s + 1];
    float dz = vtx[3 * d + 2] - vtx[3 * s + 2];
    float nx = nv.x, ny = nv.y, nz = nv.z;
    float dp = dx * nx + dy * ny + dz * nz;
    float tx = dx - dp * nx, ty = dy - dp * ny, tz = dz - dp * nz;
    float th0 = sb2[0], th1 = sb2[1], th2 = sb2[2], th3 = sb2[3], th4 = sb2[4], th5 = sb2[5];
    #pragma unroll
    for (int j = 0; j < 32; j++) {
        float h = tx * sW1[j] + ty * sW1[32 + j] + tz * sW1[64 + j] + sb1[j];
        h = fmaxf(h, 0.f);
        const float* w2r = &sW2[j * 6];
        th0 += h * w2r[0]; th1 += h * w2r[1]; th2 += h * w2r[2];
        th3 += h * w2r[3]; th4 += h * w2r[4]; th5 += h * w2r[5];
    }
    float ux = th0 * tx + th1 * ty + th2 * tz;
    float uy = th1 * tx + th3 * ty + th4 * tz;
    float uz = th2 * tx + th4 * ty + th5 * tz;
    float q = ux * ux + uy * uy + uz * uz;
    float w = expf(-q);
    unsigned int w16 = f2bf(w);
    uint2 nd;
    if (MODE == 0) {
        nd.x = (unsigned int)(old + 1) | ((w16 & 0xFFFu) << 20);
        nd.y = (unsigned int)s | ((w16 >> 12) << 17);
    } else {
        nd.x = (unsigned int)(old + 1);
        nd.y = (unsigned int)s | (w16 << 17);   // bf16 sign bit 0 => lossless 15b
    }
    enode[e] = nd;
}

// --- K4: FUSED aggregate + GEMM + bias + stats. STYLE 0: fp32 gather, partials
// only (fallback, k_rstats after). STYLE 2: bf16 gather + LAST-BLOCK stats reduce
// (device-scope counter + agent-scope loads; removes the k_rstats dispatch).
template<int STYLE>
__global__ __launch_bounds__(512) void k_fused_t(const float* __restrict__ feat,
                                                 const unsigned short* __restrict__ featb,
                                                 const int* __restrict__ head_e,
                                                 const uint2* __restrict__ enode,
                                                 const unsigned short* __restrict__ Wb,
                                                 const float* __restrict__ blin,
                                                 float* __restrict__ out,
                                                 float* __restrict__ partials,
                                                 unsigned int* cnt,
                                                 float* __restrict__ stats) {
    __shared__ __align__(16) unsigned short At[128 * 136];
    __shared__ float gs[128];
    int t = threadIdx.x;
    int g = t >> 4;
    int gl = t & 15;
    int vb = blockIdx.x * 128 + g * 4;

    float4 a0l = {0,0,0,0}, a0h = {0,0,0,0};
    float4 a1l = {0,0,0,0}, a1h = {0,0,0,0};
    float4 a2l = {0,0,0,0}, a2h = {0,0,0,0};
    float4 a3l = {0,0,0,0}, a3h = {0,0,0,0};
    float d0 = 0.f, d1 = 0.f, d2 = 0.f, d3 = 0.f;
    int e0 = (vb + 0 < N_V) ? head_e[vb + 0] : -1;
    int e1 = (vb + 1 < N_V) ? head_e[vb + 1] : -1;
    int e2 = (vb + 2 < N_V) ? head_e[vb + 2] : -1;
    int e3 = (vb + 3 < N_V) ? head_e[vb + 3] : -1;

#define CHAIN_STEP(eV, aL, aH, dV)                                                   \
    if (eV >= 0) {                                                                   \
        uint2 nd = enode[eV];                                                        \
        unsigned int w16 = (STYLE == 0)                                              \
            ? ((nd.x >> 20) | (((nd.y >> 17) & 0xFu) << 12))                         \
            : (nd.y >> 17);                                                          \
        float w = __builtin_bit_cast(float, w16 << 16);                              \
        unsigned int src = nd.y & 0x1FFFFu;                                          \
        if (STYLE < 2) {                                                             \
            const float4* fp = (const float4*)(feat + (size_t)src * 128 + 8 * gl);   \
            float4 f0 = fp[0], f1 = fp[1];                                           \
            aL.x += w * f0.x; aL.y += w * f0.y; aL.z += w * f0.z; aL.w += w * f0.w;  \
            aH.x += w * f1.x; aH.y += w * f1.y; aH.z += w * f1.z; aH.w += w * f1.w;  \
        } else {                                                                     \
            bf16x8 v = *(const bf16x8*)(featb + (size_t)src * 128 + 8 * gl);         \
            aL.x += w * bf2f(v[0]); aL.y += w * bf2f(v[1]);                          \
            aL.z += w * bf2f(v[2]); aL.w += w * bf2f(v[3]);                          \
            aH.x += w * bf2f(v[4]); aH.y += w * bf2f(v[5]);                          \
            aH.z += w * bf2f(v[6]); aH.w += w * bf2f(v[7]);                          \
        }                                                                            \
        dV += w;                                                                     \
        eV = (int)(nd.x & 0xFFFFFu) - 1;                                             \
    }

    while ((e0 >= 0) || (e1 >= 0) || (e2 >= 0) || (e3 >= 0)) {
        CHAIN_STEP(e0, a0l, a0h, d0)
        CHAIN_STEP(e1, a1l, a1h, d1)
        CHAIN_STEP(e2, a2l, a2h, d2)
        CHAIN_STEP(e3, a3l, a3h, d3)
    }
#undef CHAIN_STEP

    #pragma unroll
    for (int j = 0; j < 4; j++) {
        float4 al = (j == 0) ? a0l : (j == 1) ? a1l : (j == 2) ? a2l : a3l;
        float4 ah = (j == 0) ? a0h : (j == 1) ? a1h : (j == 2) ? a2h : a3h;
        float dn = (j == 0) ? d0 : (j == 1) ? d1 : (j == 2) ? d2 : d3;
        float inv = 1.f / (dn + 1e-5f);
        ushort4 p0, p1;
        p0.x = f2bf(al.x * inv); p0.y = f2bf(al.y * inv);
        p0.z = f2bf(al.z * inv); p0.w = f2bf(al.w * inv);
        p1.x = f2bf(ah.x * inv); p1.y = f2bf(ah.y * inv);
        p1.z = f2bf(ah.z * inv); p1.w = f2bf(ah.w * inv);
        int row = g * 4 + j;
        *(ushort4*)(&At[row * 136 + 8 * gl]) = p0;
        *(ushort4*)(&At[row * 136 + 8 * gl + 4]) = p1;
        if (gl == 0) gs[row] = dn * inv;
    }
    __syncthreads();

    int ct = t >> 6;
    int lane = t & 63;
    int m = lane & 15, quad = lane >> 4;
    bf16x8 bfr[4];
    #pragma unroll
    for (int kk = 0; kk < 4; kk++)
        bfr[kk] = *(const bf16x8*)(Wb + (((kk * 8 + ct) * 64 + lane) << 3));
    float bl = blin[ct * 16 + m];
    float ssr = 0.f, qqr = 0.f;
    #pragma unroll
    for (int tile = 0; tile < 8; tile++) {
        f32x4 acc = (f32x4){0.f, 0.f, 0.f, 0.f};
        #pragma unroll
        for (int kk = 0; kk < 4; kk++) {
            bf16x8 af = *(const bf16x8*)(&At[(tile * 16 + m) * 136 + kk * 32 + quad * 8]);
            acc = __builtin_amdgcn_mfma_f32_16x16x32_bf16(af, bfr[kk], acc, 0, 0, 0);
        }
        int r0 = blockIdx.x * 128 + tile * 16;
        #pragma unroll
        for (int reg = 0; reg < 4; reg++) {
            int r = r0 + quad * 4 + reg;
            float g2 = gs[tile * 16 + quad * 4 + reg];
            float val = acc[reg] + bl * g2;
            if (r < N_V) out[(size_t)r * 128 + ct * 16 + m] = val;
            ssr += val; qqr += val * val;
        }
    }
    ssr += __shfl_xor(ssr, 16); qqr += __shfl_xor(qqr, 16);
    ssr += __shfl_xor(ssr, 32); qqr += __shfl_xor(qqr, 32);
    if (quad == 0) {
        partials[(size_t)blockIdx.x * 256 + ct * 16 + m] = ssr;
        partials[(size_t)blockIdx.x * 256 + 128 + ct * 16 + m] = qqr;
    }

    if constexpr (STYLE == 2) {
        // last-block stats reduction (replaces k_rstats dispatch)
        __shared__ unsigned int s_last;
        __syncthreads();                       // all partials stores issued
        if (t == 0) {
            __threadfence();                   // release: publish partials agent-wide
            s_last = (atomicAdd(cnt, 1u) == FUSED_BLOCKS - 1) ? 1u : 0u;
        }
        __syncthreads();
        if (s_last) {
            __threadfence();                   // acquire side
            float* red = (float*)At;           // reuse LDS (phase 2 done)
            int col = t & 255;
            int half = t >> 8;
            float acc = 0.f;
            for (int b = half; b < FUSED_BLOCKS; b += 2)
                acc += __hip_atomic_load(&partials[(size_t)b * 256 + col],
                                         __ATOMIC_RELAXED, __HIP_MEMORY_SCOPE_AGENT);
            red[t] = acc;
            __syncthreads();
            if (t < 128) {
                float s = red[t] + red[t + 256];
                float q = red[t + 128] + red[t + 384];
                float mu = s * (1.f / N_V);
                float var = (q - s * mu) * (1.f / (N_V - 1));
                float sd = sqrtf(fmaxf(var, 0.f));
                stats[t] = mu;
                stats[128 + t] = 1.f / (sd + 1e-5f);
            }
        }
    }
}

// --- K5 (fallback): parallel partials reduction: one wave per column ---
__global__ __launch_bounds__(64) void k_rstats(const float* __restrict__ partials,
                                               float* __restrict__ stats) {
    int c = blockIdx.x;
    int lane = threadIdx.x;
    float s = 0.f, q = 0.f;
    for (int b = lane; b < FUSED_BLOCKS; b += 64) {
        s += partials[(size_t)b * 256 + c];
        q += partials[(size_t)b * 256 + 128 + c];
    }
    #pragma unroll
    for (int off = 32; off; off >>= 1) {
        s += __shfl_down(s, off);
        q += __shfl_down(q, off);
    }
    if (lane == 0) {
        float mu = s * (1.f / N_V);
        float var = (q - s * mu) * (1.f / (N_V - 1));
        float sd = sqrtf(fmaxf(var, 0.f));
        stats[c] = mu;
        stats[128 + c] = 1.f / (sd + 1e-5f);
    }
}

// --- K6: normalize + ELU, in place, float4 ---
__global__ void k_finalize(float* __restrict__ out, const float* __restrict__ stats) {
    int i = blockIdx.x * blockDim.x + threadIdx.x;
    if (i >= N_V * 32) return;
    float4 v = ((float4*)out)[i];
    int c0 = (i * 4) & 127;
    float mu0 = stats[c0], mu1 = stats[c0 + 1], mu2 = stats[c0 + 2], mu3 = stats[c0 + 3];
    float is0 = stats[128 + c0], is1 = stats[128 + c0 + 1], is2 = stats[128 + c0 + 2], is3 = stats[128 + c0 + 3];
    v.x = (v.x - mu0) * is0; v.y = (v.y - mu1) * is1;
    v.z = (v.z - mu2) * is2; v.w = (v.w - mu3) * is3;
    v.x = v.x > 0.f ? v.x : expm1f(v.x);
    v.y = v.y > 0.f ? v.y : expm1f(v.y);
    v.z = v.z > 0.f ? v.z : expm1f(v.z);
    v.w = v.w > 0.f ? v.w : expm1f(v.w);
    ((float4*)out)[i] = v;
}

extern "C" void kernel_launch(void* const* d_in, const int* in_sizes, int n_in,
                              void* d_out, int out_size, void* d_ws, size_t ws_size,
                              hipStream_t stream) {
    const float* feat  = (const float*)d_in[0];
    const float* vtx   = (const float*)d_in[1];
    const int*   edges = (const int*)d_in[2];
    const int*   faces = (const int*)d_in[3];
    const float* W1   = (const float*)d_in[4];
    const float* b1   = (const float*)d_in[5];
    const float* W2   = (const float*)d_in[6];
    const float* b2   = (const float*)d_in[7];
    const float* Wlin = (const float*)d_in[8];
    const float* blin = (const float*)d_in[9];
    float* out = (float*)d_out;
    float* ws = (float*)d_ws;

    // r11-proven aliased layout:
    //   head_e [0,100000) ; head_f [100000,200000) ; nrm4 [200000,600000)
    //   partials alias [100000,300192) after k_edge
    //   cnt [600000,600001) — free gap (nrm4 ends 600000, next_f starts 600128)
    //   next_f [600128,1200128) ; fnbuf4 [1200128,2000128)
    //   enode alias [600128,1800128) after k_vnorm
    //   Wb [2000128,2008320) ; featb [2008320,8408320) (tier 2 only)
    int*   head_e   = (int*)ws;
    int*   head_f   = (int*)(ws + 100000);
    float4* nrm4    = (float4*)(ws + 200000);
    float* partials = ws + 100000;
    unsigned int* cnt = (unsigned int*)(ws + 600000);
    int*   next_f   = (int*)(ws + 600128);
    float4* fnbuf4  = (float4*)(ws + 1200128);
    uint2* enode    = (uint2*)(ws + 600128);
    unsigned short* Wb = (unsigned short*)(ws + 2000128);
    unsigned short* featb = (unsigned short*)(ws + 2008320);
    float* stats    = ws;

    // tier 2 needs featb: 8,408,320 floats = 33.63 MB (ws proven >= 38.4 MB in r9)
    const size_t NEED2 = 8408320u * 4u;
    int tier2 = (ws_size >= NEED2) ? 1 : 0;

    hipMemsetAsync(head_e, 0xFF, 200000 * sizeof(int), stream);   // head_e + head_f

    int fn_grid = FACE_BLOCKS + PACK_BLOCKS + (tier2 ? CONV_BLOCKS : 0);
    k_fn<<<fn_grid, 256, 0, stream>>>(vtx, faces, Wlin, feat, fnbuf4,
                                      head_f, next_f, Wb, tier2 ? featb : nullptr);
    k_vnorm<<<(N_V + 255) / 256, 256, 0, stream>>>(fnbuf4, head_f, next_f, nrm4);
    if (tier2) {
        k_edge_t<1><<<EDGE_BLOCKS, 256, 0, stream>>>(vtx, edges, nrm4, W1, b1, W2, b2,
                                                     head_e, enode, cnt);
        k_fused_t<2><<<FUSED_BLOCKS, 512, 0, stream>>>(feat, featb, head_e, enode, Wb,
                                                       blin, out, partials, cnt, stats);
        k_finalize<<<(N_V * 32 + 255) / 256, 256, 0, stream>>>(out, stats);
    } else {
        k_edge_t<0><<<EDGE_BLOCKS, 256, 0, stream>>>(vtx, edges, nrm4, W1, b1, W2, b2,
                                                     head_e, enode, nullptr);
        k_fused_t<0><<<FUSED_BLOCKS, 512, 0, stream>>>(feat, nullptr, head_e, enode, Wb,
                                                       blin, out, partials, nullptr, nullptr);
        k_rstats<<<128, 64, 0, stream>>>(partials, stats);
        k_finalize<<<(N_V * 32 + 255) / 256, 256, 0, stream>>>(out, stats);
    }
}

// Round 15
// 256.039 us; speedup vs baseline: 1.5492x; 1.5492x over previous
//
#include <hip/hip_runtime.h>
#include <hip/hip_bf16.h>
#include <math.h>

#define N_V 100000
#define N_E 600000
#define N_F 200000
// CIN = COUT = 128, H = 32

typedef __attribute__((ext_vector_type(8))) short bf16x8;
typedef __attribute__((ext_vector_type(4))) float f32x4;

#define FUSED_BLOCKS 782                    // ceil(100000/128); 128 rows per block
#define FACE_BLOCKS 782                     // ceil(200000/256)
#define EDGE_BLOCKS 2344                    // ceil(600000/256)
#define PACK_BLOCKS 64
#define CONV_BLOCKS 6250                    // 100000*128 bf16 conversions / (256*8)

__device__ __forceinline__ unsigned short f2bf(float f) {
    unsigned int u = __builtin_bit_cast(unsigned int, f);
    u += 0x7fffu + ((u >> 16) & 1u);   // round-to-nearest-even
    return (unsigned short)(u >> 16);
}
__device__ __forceinline__ float bf2f(short s) {
    return __builtin_bit_cast(float, ((unsigned int)(unsigned short)s) << 16);
}

// --- K1: faces (normals + corner list push) + Wlin pack (+ feat->bf16 conv).
// Pinned lessons: edge atomics live in k_edge (r10: co-located atomics serialize at
// ~19G/s); inline normal walk 6x traffic (r12); k_back redundant reduce +10us (r13);
// last-block agent-scope reduce +143us (r14: agent atomics bypass L2 on gfx950).
__global__ void k_fn(const float* __restrict__ vtx, const int* __restrict__ faces,
                     const float* __restrict__ Wlin, const float* __restrict__ feat,
                     float4* __restrict__ fnbuf4,
                     int* __restrict__ head_f, int* __restrict__ next_f,
                     unsigned short* __restrict__ Wb,
                     unsigned short* __restrict__ featb) {
    int b = blockIdx.x;
    int t = threadIdx.x;
    if (b < FACE_BLOCKS) {
        int f = b * 256 + t;
        if (f >= N_F) return;
        int i0 = faces[f], i1 = faces[N_F + f], i2 = faces[2 * N_F + f];
        #pragma unroll
        for (int j = 0; j < 3; j++) {
            int v = (j == 0) ? i0 : (j == 1 ? i1 : i2);
            int c = 3 * f + j;
            int old = atomicExch(&head_f[v], c);
            next_f[c] = old;
        }
        float ax = vtx[3 * i0], ay = vtx[3 * i0 + 1], az = vtx[3 * i0 + 2];
        float bx = vtx[3 * i1] - ax, by = vtx[3 * i1 + 1] - ay, bz = vtx[3 * i1 + 2] - az;
        float cx = vtx[3 * i2] - ax, cy = vtx[3 * i2 + 1] - ay, cz = vtx[3 * i2 + 2] - az;
        float4 fn;
        fn.x = by * cz - bz * cy;
        fn.y = bz * cx - bx * cz;
        fn.z = bx * cy - by * cx;
        fn.w = 0.f;
        fnbuf4[f] = fn;
    } else if (b < FACE_BLOCKS + PACK_BLOCKS) {
        // pack Wlin (fp32 [128,128]) into bf16 MFMA B-fragment order
        int i = (b - FACE_BLOCKS) * 256 + t;   // 0..16383
        int j = i & 7;
        int lane = (i >> 3) & 63;
        int ct = (i >> 9) & 7;
        int kk = i >> 12;
        int k = kk * 32 + (lane >> 4) * 8 + j;
        int n = ct * 16 + (lane & 15);
        Wb[i] = f2bf(Wlin[k * 128 + n]);
    } else {
        // feat fp32 -> bf16 row-major copy (streamed, 8 elems/thread)
        int i = (b - FACE_BLOCKS - PACK_BLOCKS) * 256 + t;
        const float4* fp = (const float4*)(feat + (size_t)i * 8);
        float4 f0 = fp[0], f1 = fp[1];
        bf16x8 p;
        p[0] = (short)f2bf(f0.x); p[1] = (short)f2bf(f0.y);
        p[2] = (short)f2bf(f0.z); p[3] = (short)f2bf(f0.w);
        p[4] = (short)f2bf(f1.x); p[5] = (short)f2bf(f1.y);
        p[6] = (short)f2bf(f1.z); p[7] = (short)f2bf(f1.w);
        *(bf16x8*)(featb + (size_t)i * 8) = p;
    }
}

// --- K2 (main): vertex normals via corner-list walk; writes interleaved
// vn[2v]=position, vn[2v+1]=normal so k_edge does 3x16B gathers instead of
// 6 scalar vtx loads + 1 nrm gather (7 transactions -> 3).
__global__ void k_vnorm2(const float* __restrict__ vtx,
                         const float4* __restrict__ fnbuf4,
                         const int* __restrict__ head_f, const int* __restrict__ next_f,
                         float4* __restrict__ vn) {
    int v = blockIdx.x * 256 + threadIdx.x;
    if (v >= N_V) return;
    float nx = 0.f, ny = 0.f, nz = 0.f;
    int c = head_f[v];
    while (c >= 0) {
        float4 fn = fnbuf4[(unsigned)c / 3u];
        nx += fn.x; ny += fn.y; nz += fn.z;
        c = next_f[c];
    }
    float inv = 1.f / (sqrtf(nx * nx + ny * ny + nz * nz) + 1e-8f);
    float4 p, o;
    p.x = vtx[3 * v]; p.y = vtx[3 * v + 1]; p.z = vtx[3 * v + 2]; p.w = 0.f;
    o.x = nx * inv; o.y = ny * inv; o.z = nz * inv; o.w = 0.f;
    vn[2 * (size_t)v] = p;
    vn[2 * (size_t)v + 1] = o;
}

// --- K2 (fallback): r11 nrm4 variant ---
__global__ void k_vnorm(const float4* __restrict__ fnbuf4,
                        const int* __restrict__ head_f, const int* __restrict__ next_f,
                        float4* __restrict__ nrm4) {
    int v = blockIdx.x * 256 + threadIdx.x;
    if (v >= N_V) return;
    float nx = 0.f, ny = 0.f, nz = 0.f;
    int c = head_f[v];
    while (c >= 0) {
        float4 fn = fnbuf4[(unsigned)c / 3u];
        nx += fn.x; ny += fn.y; nz += fn.z;
        c = next_f[c];
    }
    float inv = 1.f / (sqrtf(nx * nx + ny * ny + nz * nz) + 1e-8f);
    float4 o;
    o.x = nx * inv; o.y = ny * inv; o.z = nz * inv; o.w = 0.f;
    nrm4[v] = o;
}

// --- K3 (main): per-edge MLP + atomicExch push; geometry via 3x16B vn gathers.
// w15 pack (nd.y = src | w16<<17; w>0 => bf16 sign bit 0 => lossless).
__global__ void k_edge2(const int* __restrict__ edges,
                        const float4* __restrict__ vn,
                        const float* __restrict__ W1, const float* __restrict__ b1,
                        const float* __restrict__ W2, const float* __restrict__ b2,
                        int* __restrict__ head_e, uint2* __restrict__ enode) {
    __shared__ float sW1[96], sb1[32], sW2[192], sb2[6];
    int t = threadIdx.x;
    if (t < 96)  sW1[t] = W1[t];
    if (t < 32)  sb1[t] = b1[t];
    if (t < 192) sW2[t] = W2[t];
    if (t < 6)   sb2[t] = b2[t];
    __syncthreads();
    int e = blockIdx.x * blockDim.x + t;
    if (e >= N_E) return;
    int s = edges[e], d = edges[N_E + e];
    int old = atomicExch(&head_e[d], e);      // issue early; hides under MLP
    float4 ps = vn[2 * (size_t)s];
    float4 ns = vn[2 * (size_t)s + 1];
    float4 pd = vn[2 * (size_t)d];
    float dx = pd.x - ps.x, dy = pd.y - ps.y, dz = pd.z - ps.z;
    float nx = ns.x, ny = ns.y, nz = ns.z;
    float dp = dx * nx + dy * ny + dz * nz;
    float tx = dx - dp * nx, ty = dy - dp * ny, tz = dz - dp * nz;
    float th0 = sb2[0], th1 = sb2[1], th2 = sb2[2], th3 = sb2[3], th4 = sb2[4], th5 = sb2[5];
    #pragma unroll
    for (int j = 0; j < 32; j++) {
        float h = tx * sW1[j] + ty * sW1[32 + j] + tz * sW1[64 + j] + sb1[j];
        h = fmaxf(h, 0.f);
        const float* w2r = &sW2[j * 6];
        th0 += h * w2r[0]; th1 += h * w2r[1]; th2 += h * w2r[2];
        th3 += h * w2r[3]; th4 += h * w2r[4]; th5 += h * w2r[5];
    }
    float ux = th0 * tx + th1 * ty + th2 * tz;
    float uy = th1 * tx + th3 * ty + th4 * tz;
    float uz = th2 * tx + th4 * ty + th5 * tz;
    float q = ux * ux + uy * uy + uz * uz;
    float w = expf(-q);
    unsigned int w16 = f2bf(w);
    uint2 nd;
    nd.x = (unsigned int)(old + 1);
    nd.y = (unsigned int)s | (w16 << 17);
    enode[e] = nd;
}

// --- K3 (fallback): r11 split-w variant with nrm4 + scalar vtx ---
__global__ void k_edge0(const float* __restrict__ vtx, const int* __restrict__ edges,
                        const float4* __restrict__ nrm4,
                        const float* __restrict__ W1, const float* __restrict__ b1,
                        const float* __restrict__ W2, const float* __restrict__ b2,
                        int* __restrict__ head_e, uint2* __restrict__ enode) {
    __shared__ float sW1[96], sb1[32], sW2[192], sb2[6];
    int t = threadIdx.x;
    if (t < 96)  sW1[t] = W1[t];
    if (t < 32)  sb1[t] = b1[t];
    if (t < 192) sW2[t] = W2[t];
    if (t < 6)   sb2[t] = b2[t];
    __syncthreads();
    int e = blockIdx.x * blockDim.x + t;
    if (e >= N_E) return;
    int s = edges[e], d = edges[N_E + e];
    int old = atomicExch(&head_e[d], e);
    float4 nv = nrm4[s];
    float dx = vtx[3 * d] - vtx[3 * s];
    float dy = vtx[3 * d + 1] - vtx[3 * s + 1];
    float dz = vtx[3 * d + 2] - vtx[3 * s + 2];
    float nx = nv.x, ny = nv.y, nz = nv.z;
    float dp = dx * nx + dy * ny + dz * nz;
    float tx = dx - dp * nx, ty = dy - dp * ny, tz = dz - dp * nz;
    float th0 = sb2[0], th1 = sb2[1], th2 = sb2[2], th3 = sb2[3], th4 = sb2[4], th5 = sb2[5];
    #pragma unroll
    for (int j = 0; j < 32; j++) {
        float h = tx * sW1[j] + ty * sW1[32 + j] + tz * sW1[64 + j] + sb1[j];
        h = fmaxf(h, 0.f);
        const float* w2r = &sW2[j * 6];
        th0 += h * w2r[0]; th1 += h * w2r[1]; th2 += h * w2r[2];
        th3 += h * w2r[3]; th4 += h * w2r[4]; th5 += h * w2r[5];
    }
    float ux = th0 * tx + th1 * ty + th2 * tz;
    float uy = th1 * tx + th3 * ty + th4 * tz;
    float uz = th2 * tx + th4 * ty + th5 * tz;
    float q = ux * ux + uy * uy + uz * uz;
    float w = expf(-q);
    unsigned int w16 = f2bf(w);
    uint2 nd;
    nd.x = (unsigned int)(old + 1) | ((w16 & 0xFFFu) << 20);
    nd.y = (unsigned int)s | ((w16 >> 12) << 17);
    enode[e] = nd;
}

// --- K4: FUSED aggregate + GEMM + bias + stats partials (r11 proven, untouched).
// STYLE: 0=split-w fp32 gather (fallback), 2=w15 bf16 gather (main).
template<int STYLE>
__global__ __launch_bounds__(512) void k_fused_t(const float* __restrict__ feat,
                                                 const unsigned short* __restrict__ featb,
                                                 const int* __restrict__ head_e,
                                                 const uint2* __restrict__ enode,
                                                 const unsigned short* __restrict__ Wb,
                                                 const float* __restrict__ blin,
                                                 float* __restrict__ out,
                                                 float* __restrict__ partials) {
    __shared__ __align__(16) unsigned short At[128 * 136];
    __shared__ float gs[128];
    int t = threadIdx.x;
    int g = t >> 4;
    int gl = t & 15;
    int vb = blockIdx.x * 128 + g * 4;

    float4 a0l = {0,0,0,0}, a0h = {0,0,0,0};
    float4 a1l = {0,0,0,0}, a1h = {0,0,0,0};
    float4 a2l = {0,0,0,0}, a2h = {0,0,0,0};
    float4 a3l = {0,0,0,0}, a3h = {0,0,0,0};
    float d0 = 0.f, d1 = 0.f, d2 = 0.f, d3 = 0.f;
    int e0 = (vb + 0 < N_V) ? head_e[vb + 0] : -1;
    int e1 = (vb + 1 < N_V) ? head_e[vb + 1] : -1;
    int e2 = (vb + 2 < N_V) ? head_e[vb + 2] : -1;
    int e3 = (vb + 3 < N_V) ? head_e[vb + 3] : -1;

#define CHAIN_STEP(eV, aL, aH, dV)                                                   \
    if (eV >= 0) {                                                                   \
        uint2 nd = enode[eV];                                                        \
        unsigned int w16 = (STYLE == 0)                                              \
            ? ((nd.x >> 20) | (((nd.y >> 17) & 0xFu) << 12))                         \
            : (nd.y >> 17);                                                          \
        float w = __builtin_bit_cast(float, w16 << 16);                              \
        unsigned int src = nd.y & 0x1FFFFu;                                          \
        if (STYLE < 2) {                                                             \
            const float4* fp = (const float4*)(feat + (size_t)src * 128 + 8 * gl);   \
            float4 f0 = fp[0], f1 = fp[1];                                           \
            aL.x += w * f0.x; aL.y += w * f0.y; aL.z += w * f0.z; aL.w += w * f0.w;  \
            aH.x += w * f1.x; aH.y += w * f1.y; aH.z += w * f1.z; aH.w += w * f1.w;  \
        } else {                                                                     \
            bf16x8 v = *(const bf16x8*)(featb + (size_t)src * 128 + 8 * gl);         \
            aL.x += w * bf2f(v[0]); aL.y += w * bf2f(v[1]);                          \
            aL.z += w * bf2f(v[2]); aL.w += w * bf2f(v[3]);                          \
            aH.x += w * bf2f(v[4]); aH.y += w * bf2f(v[5]);                          \
            aH.z += w * bf2f(v[6]); aH.w += w * bf2f(v[7]);                          \
        }                                                                            \
        dV += w;                                                                     \
        eV = (int)(nd.x & 0xFFFFFu) - 1;                                             \
    }

    while ((e0 >= 0) || (e1 >= 0) || (e2 >= 0) || (e3 >= 0)) {
        CHAIN_STEP(e0, a0l, a0h, d0)
        CHAIN_STEP(e1, a1l, a1h, d1)
        CHAIN_STEP(e2, a2l, a2h, d2)
        CHAIN_STEP(e3, a3l, a3h, d3)
    }
#undef CHAIN_STEP

    #pragma unroll
    for (int j = 0; j < 4; j++) {
        float4 al = (j == 0) ? a0l : (j == 1) ? a1l : (j == 2) ? a2l : a3l;
        float4 ah = (j == 0) ? a0h : (j == 1) ? a1h : (j == 2) ? a2h : a3h;
        float dn = (j == 0) ? d0 : (j == 1) ? d1 : (j == 2) ? d2 : d3;
        float inv = 1.f / (dn + 1e-5f);
        ushort4 p0, p1;
        p0.x = f2bf(al.x * inv); p0.y = f2bf(al.y * inv);
        p0.z = f2bf(al.z * inv); p0.w = f2bf(al.w * inv);
        p1.x = f2bf(ah.x * inv); p1.y = f2bf(ah.y * inv);
        p1.z = f2bf(ah.z * inv); p1.w = f2bf(ah.w * inv);
        int row = g * 4 + j;
        *(ushort4*)(&At[row * 136 + 8 * gl]) = p0;
        *(ushort4*)(&At[row * 136 + 8 * gl + 4]) = p1;
        if (gl == 0) gs[row] = dn * inv;
    }
    __syncthreads();

    int ct = t >> 6;
    int lane = t & 63;
    int m = lane & 15, quad = lane >> 4;
    bf16x8 bfr[4];
    #pragma unroll
    for (int kk = 0; kk < 4; kk++)
        bfr[kk] = *(const bf16x8*)(Wb + (((kk * 8 + ct) * 64 + lane) << 3));
    float bl = blin[ct * 16 + m];
    float ssr = 0.f, qqr = 0.f;
    #pragma unroll
    for (int tile = 0; tile < 8; tile++) {
        f32x4 acc = (f32x4){0.f, 0.f, 0.f, 0.f};
        #pragma unroll
        for (int kk = 0; kk < 4; kk++) {
            bf16x8 af = *(const bf16x8*)(&At[(tile * 16 + m) * 136 + kk * 32 + quad * 8]);
            acc = __builtin_amdgcn_mfma_f32_16x16x32_bf16(af, bfr[kk], acc, 0, 0, 0);
        }
        int r0 = blockIdx.x * 128 + tile * 16;
        #pragma unroll
        for (int reg = 0; reg < 4; reg++) {
            int r = r0 + quad * 4 + reg;
            float g2 = gs[tile * 16 + quad * 4 + reg];
            float val = acc[reg] + bl * g2;
            if (r < N_V) out[(size_t)r * 128 + ct * 16 + m] = val;
            ssr += val; qqr += val * val;
        }
    }
    ssr += __shfl_xor(ssr, 16); qqr += __shfl_xor(qqr, 16);
    ssr += __shfl_xor(ssr, 32); qqr += __shfl_xor(qqr, 32);
    if (quad == 0) {
        partials[(size_t)blockIdx.x * 256 + ct * 16 + m] = ssr;
        partials[(size_t)blockIdx.x * 256 + 128 + ct * 16 + m] = qqr;
    }
}

// --- K5: parallel partials reduction: one wave per column (3us; proven optimal) ---
__global__ __launch_bounds__(64) void k_rstats(const float* __restrict__ partials,
                                               float* __restrict__ stats) {
    int c = blockIdx.x;
    int lane = threadIdx.x;
    float s = 0.f, q = 0.f;
    for (int b = lane; b < FUSED_BLOCKS; b += 64) {
        s += partials[(size_t)b * 256 + c];
        q += partials[(size_t)b * 256 + 128 + c];
    }
    #pragma unroll
    for (int off = 32; off; off >>= 1) {
        s += __shfl_down(s, off);
        q += __shfl_down(q, off);
    }
    if (lane == 0) {
        float mu = s * (1.f / N_V);
        float var = (q - s * mu) * (1.f / (N_V - 1));
        float sd = sqrtf(fmaxf(var, 0.f));
        stats[c] = mu;
        stats[128 + c] = 1.f / (sd + 1e-5f);
    }
}

// --- K6: normalize + ELU, in place, float4 ---
__global__ void k_finalize(float* __restrict__ out, const float* __restrict__ stats) {
    int i = blockIdx.x * blockDim.x + threadIdx.x;
    if (i >= N_V * 32) return;
    float4 v = ((float4*)out)[i];
    int c0 = (i * 4) & 127;
    float mu0 = stats[c0], mu1 = stats[c0 + 1], mu2 = stats[c0 + 2], mu3 = stats[c0 + 3];
    float is0 = stats[128 + c0], is1 = stats[128 + c0 + 1], is2 = stats[128 + c0 + 2], is3 = stats[128 + c0 + 3];
    v.x = (v.x - mu0) * is0; v.y = (v.y - mu1) * is1;
    v.z = (v.z - mu2) * is2; v.w = (v.w - mu3) * is3;
    v.x = v.x > 0.f ? v.x : expm1f(v.x);
    v.y = v.y > 0.f ? v.y : expm1f(v.y);
    v.z = v.z > 0.f ? v.z : expm1f(v.z);
    v.w = v.w > 0.f ? v.w : expm1f(v.w);
    ((float4*)out)[i] = v;
}

extern "C" void kernel_launch(void* const* d_in, const int* in_sizes, int n_in,
                              void* d_out, int out_size, void* d_ws, size_t ws_size,
                              hipStream_t stream) {
    const float* feat  = (const float*)d_in[0];
    const float* vtx   = (const float*)d_in[1];
    const int*   edges = (const int*)d_in[2];
    const int*   faces = (const int*)d_in[3];
    const float* W1   = (const float*)d_in[4];
    const float* b1   = (const float*)d_in[5];
    const float* W2   = (const float*)d_in[6];
    const float* b2   = (const float*)d_in[7];
    const float* Wlin = (const float*)d_in[8];
    const float* blin = (const float*)d_in[9];
    float* out = (float*)d_out;
    float* ws = (float*)d_ws;

    // Main (tier2) layout, floats — total 9,208,320 = 36.83 MB (< r9-proven 38.43):
    //   head_e [0,100000) ; head_f [100000,200000)
    //   partials alias [100000,300192) after k_vnorm2 (head_f dead)
    //   next_f [600128,1200128) ; fnbuf4 [1200128,2000128)
    //   enode alias [600128,1800128) after k_vnorm2
    //   Wb [2000128,2008320) ; featb [2008320,8408320)
    //   vn [8408320,9208320) — 100000 x 2 float4 {pos, nrm}
    //   stats alias ws[0,256) after k_fused
    int*   head_e   = (int*)ws;
    int*   head_f   = (int*)(ws + 100000);
    float4* nrm4    = (float4*)(ws + 200000);            // fallback only
    float* partials = ws + 100000;
    int*   next_f   = (int*)(ws + 600128);
    float4* fnbuf4  = (float4*)(ws + 1200128);
    uint2* enode    = (uint2*)(ws + 600128);
    unsigned short* Wb = (unsigned short*)(ws + 2000128);
    unsigned short* featb = (unsigned short*)(ws + 2008320);
    float4* vn      = (float4*)(ws + 8408320);
    float* stats    = ws;

    const size_t NEED2 = 9208320u * 4u;
    int tier2 = (ws_size >= NEED2) ? 1 : 0;

    hipMemsetAsync(head_e, 0xFF, 200000 * sizeof(int), stream);   // head_e + head_f

    int fn_grid = FACE_BLOCKS + PACK_BLOCKS + (tier2 ? CONV_BLOCKS : 0);
    k_fn<<<fn_grid, 256, 0, stream>>>(vtx, faces, Wlin, feat, fnbuf4,
                                      head_f, next_f, Wb, tier2 ? featb : nullptr);
    if (tier2) {
        k_vnorm2<<<(N_V + 255) / 256, 256, 0, stream>>>(vtx, fnbuf4, head_f, next_f, vn);
        k_edge2<<<EDGE_BLOCKS, 256, 0, stream>>>(edges, vn, W1, b1, W2, b2,
                                                 head_e, enode);
        k_fused_t<2><<<FUSED_BLOCKS, 512, 0, stream>>>(feat, featb, head_e, enode, Wb,
                                                       blin, out, partials);
    } else {
        k_vnorm<<<(N_V + 255) / 256, 256, 0, stream>>>(fnbuf4, head_f, next_f, nrm4);
        k_edge0<<<EDGE_BLOCKS, 256, 0, stream>>>(vtx, edges, nrm4, W1, b1, W2, b2,
                                                 head_e, enode);
        k_fused_t<0><<<FUSED_BLOCKS, 512, 0, stream>>>(feat, nullptr, head_e, enode, Wb,
                                                       blin, out, partials);
    }
    k_rstats<<<128, 64, 0, stream>>>(partials, stats);
    k_finalize<<<(N_V * 32 + 255) / 256, 256, 0, stream>>>(out, stats);
}